// Round 1
// baseline (253.252 us; speedup 1.0000x reference)
//
#include <hip/hip_runtime.h>
#include <math.h>

#define NKNOTS 10
#define RED_BLOCKS 1024
#define RED_THREADS 256
#define EVAL_BLOCKS 4096
#define EVAL_THREADS 256

// ws float layout:
//   [0]      x_min
//   [1]      denom = x_max - x_min + 1e-8
//   [2..10]  inv1[9]  (d=1: 1/(t[j+1]-t[j]) or 0)
//   [11..18] inv2[8]  (d=2)
//   [19..25] inv3[7]  (d=3)
//   [32..32+RED_BLOCKS)            block mins
//   [32+RED_BLOCKS..32+2*RED_BLOCKS) block maxs

__device__ __forceinline__ void bspline6(float x, const float* __restrict__ t,
                                         const float* __restrict__ inv1,
                                         const float* __restrict__ inv2,
                                         const float* __restrict__ inv3,
                                         float* __restrict__ out) {
    float B[9];
    const bool at_end = (x == t[9]);
#pragma unroll
    for (int j = 0; j < 9; ++j) {
        float b = (x >= t[j] && x < t[j + 1]) ? 1.0f : 0.0f;
        if (at_end && (t[j + 1] == t[9]) && (t[j] < t[j + 1])) b = 1.0f;
        B[j] = b;
    }
#pragma unroll
    for (int j = 0; j < 8; ++j) {
        float w1 = (x - t[j]) * inv1[j];
        float w2 = (t[j + 2] - x) * inv1[j + 1];
        B[j] = w1 * B[j] + w2 * B[j + 1];
    }
#pragma unroll
    for (int j = 0; j < 7; ++j) {
        float w1 = (x - t[j]) * inv2[j];
        float w2 = (t[j + 3] - x) * inv2[j + 1];
        B[j] = w1 * B[j] + w2 * B[j + 1];
    }
#pragma unroll
    for (int j = 0; j < 6; ++j) {
        float w1 = (x - t[j]) * inv3[j];
        float w2 = (t[j + 4] - x) * inv3[j + 1];
        out[j] = w1 * B[j] + w2 * B[j + 1];
    }
}

__global__ void reduce_minmax_kernel(const float* __restrict__ x, int n,
                                     float* __restrict__ bmin,
                                     float* __restrict__ bmax) {
    float lmin = INFINITY, lmax = -INFINITY;
    int tid = blockIdx.x * blockDim.x + threadIdx.x;
    int stride = gridDim.x * blockDim.x;
    int n4 = n >> 2;
    const float4* x4 = reinterpret_cast<const float4*>(x);
    for (int i = tid; i < n4; i += stride) {
        float4 v = x4[i];
        lmin = fminf(lmin, fminf(fminf(v.x, v.y), fminf(v.z, v.w)));
        lmax = fmaxf(lmax, fmaxf(fmaxf(v.x, v.y), fmaxf(v.z, v.w)));
    }
    for (int i = (n4 << 2) + tid; i < n; i += stride) {
        float v = x[i];
        lmin = fminf(lmin, v);
        lmax = fmaxf(lmax, v);
    }
#pragma unroll
    for (int off = 32; off > 0; off >>= 1) {
        lmin = fminf(lmin, __shfl_down(lmin, off));
        lmax = fmaxf(lmax, __shfl_down(lmax, off));
    }
    __shared__ float smin[RED_THREADS / 64], smax[RED_THREADS / 64];
    int wave = threadIdx.x >> 6;
    if ((threadIdx.x & 63) == 0) { smin[wave] = lmin; smax[wave] = lmax; }
    __syncthreads();
    if (threadIdx.x == 0) {
        float m = smin[0], M = smax[0];
#pragma unroll
        for (int w = 1; w < RED_THREADS / 64; ++w) {
            m = fminf(m, smin[w]);
            M = fmaxf(M, smax[w]);
        }
        bmin[blockIdx.x] = m;
        bmax[blockIdx.x] = M;
    }
}

__global__ void finalize_kernel(const float* __restrict__ bmin,
                                const float* __restrict__ bmax, int nb,
                                const float* __restrict__ knots,
                                float* __restrict__ params) {
    float lmin = INFINITY, lmax = -INFINITY;
    for (int i = threadIdx.x; i < nb; i += blockDim.x) {
        lmin = fminf(lmin, bmin[i]);
        lmax = fmaxf(lmax, bmax[i]);
    }
#pragma unroll
    for (int off = 32; off > 0; off >>= 1) {
        lmin = fminf(lmin, __shfl_down(lmin, off));
        lmax = fmaxf(lmax, __shfl_down(lmax, off));
    }
    __shared__ float smin[4], smax[4];
    int wave = threadIdx.x >> 6;
    if ((threadIdx.x & 63) == 0) { smin[wave] = lmin; smax[wave] = lmax; }
    __syncthreads();
    if (threadIdx.x == 0) {
        float m = smin[0], M = smax[0];
#pragma unroll
        for (int w = 1; w < 4; ++w) {
            m = fminf(m, smin[w]);
            M = fmaxf(M, smax[w]);
        }
        params[0] = m;
        params[1] = M - m + 1e-8f;
        float t[NKNOTS];
#pragma unroll
        for (int j = 0; j < NKNOTS; ++j) t[j] = knots[j];
        int idx = 2;
        for (int d = 1; d <= 3; ++d) {
            for (int j = 0; j + d <= NKNOTS - 1; ++j) {
                float den = t[j + d] - t[j];
                params[idx++] = (den > 0.0f) ? (1.0f / den) : 0.0f;
            }
        }
    }
}

__global__ void eval_kernel(const float* __restrict__ x,
                            const float* __restrict__ knots,
                            const float* __restrict__ params,
                            float* __restrict__ out, int n) {
    float t[NKNOTS];
#pragma unroll
    for (int j = 0; j < NKNOTS; ++j) t[j] = knots[j];
    const float xmin = params[0];
    const float denom = params[1];
    float inv1[9], inv2[8], inv3[7];
#pragma unroll
    for (int j = 0; j < 9; ++j) inv1[j] = params[2 + j];
#pragma unroll
    for (int j = 0; j < 8; ++j) inv2[j] = params[11 + j];
#pragma unroll
    for (int j = 0; j < 7; ++j) inv3[j] = params[19 + j];

    int tid = blockIdx.x * blockDim.x + threadIdx.x;
    int stride = gridDim.x * blockDim.x;
    int npair = n >> 1;
    const float2* x2 = reinterpret_cast<const float2*>(x);
    float4* out4 = reinterpret_cast<float4*>(out);
    for (int p = tid; p < npair; p += stride) {
        float2 v = x2[p];
        // true IEEE division to exactly match reference normalization
        // (the max element must land on exactly 1.0 to hit the clamped
        //  right-endpoint rule; reciprocal-multiply can miss by 1 ulp)
        float a = (v.x - xmin) / denom;
        float b = (v.y - xmin) / denom;
        float oa[6], ob[6];
        bspline6(a, t, inv1, inv2, inv3, oa);
        bspline6(b, t, inv1, inv2, inv3, ob);
        float4* o = out4 + (size_t)p * 3;
        o[0] = make_float4(oa[0], oa[1], oa[2], oa[3]);
        o[1] = make_float4(oa[4], oa[5], ob[0], ob[1]);
        o[2] = make_float4(ob[2], ob[3], ob[4], ob[5]);
    }
    if ((n & 1) && tid == 0) {
        float a = (x[n - 1] - xmin) / denom;
        float oa[6];
        bspline6(a, t, inv1, inv2, inv3, oa);
#pragma unroll
        for (int k = 0; k < 6; ++k) out[(size_t)(n - 1) * 6 + k] = oa[k];
    }
}

extern "C" void kernel_launch(void* const* d_in, const int* in_sizes, int n_in,
                              void* d_out, int out_size, void* d_ws, size_t ws_size,
                              hipStream_t stream) {
    const float* x = (const float*)d_in[0];
    const float* knots = (const float*)d_in[1];
    float* out = (float*)d_out;
    int n = in_sizes[0];

    float* wsf = (float*)d_ws;
    float* params = wsf;                 // 32 floats reserved
    float* bmin = wsf + 32;              // RED_BLOCKS floats
    float* bmax = wsf + 32 + RED_BLOCKS; // RED_BLOCKS floats

    reduce_minmax_kernel<<<RED_BLOCKS, RED_THREADS, 0, stream>>>(x, n, bmin, bmax);
    finalize_kernel<<<1, 256, 0, stream>>>(bmin, bmax, RED_BLOCKS, knots, params);
    eval_kernel<<<EVAL_BLOCKS, EVAL_THREADS, 0, stream>>>(x, knots, params, out, n);
}